// Round 1
// baseline (1200.871 us; speedup 1.0000x reference)
//
#include <hip/hip_runtime.h>
#include <cstddef>

static constexpr int T_STEPS = 100;
static constexpr int FEAT = 40;
static constexpr int SMEM_BYTES = 137216;

__device__ __forceinline__ float fast_sig(float x) {
  return __builtin_amdgcn_rcpf(1.0f + __expf(-x));
}
__device__ __forceinline__ float fast_tanh(float x) {
  return 2.0f * __builtin_amdgcn_rcpf(1.0f + __expf(-2.0f * x)) - 1.0f;
}
__device__ __forceinline__ float f4c(float4 v, int e) {
  switch (e & 3) { case 0: return v.x; case 1: return v.y; case 2: return v.z; default: return v.w; }
}
__device__ __forceinline__ void fma4(float4& a, float4 w, float s) {
  a.x = fmaf(w.x, s, a.x);
  a.y = fmaf(w.y, s, a.y);
  a.z = fmaf(w.z, s, a.z);
  a.w = fmaf(w.w, s, a.w);
}

// One block = 16 batch elems through the WHOLE pipeline (enc -> lat -> dec -> proj).
// tid = bs*64 + j : wave bs handles batch sub-group {bs*4..bs*4+3}, lane j owns hidden unit j
// (computes its 4 gates i,f,g,o as a float4). Weights transposed in LDS as [k][unit]{i,f,g,o}
// so lane-consecutive ds_read_b128 is conflict-free; activation reads are wave-uniform (broadcast).
extern "C" __global__ __launch_bounds__(256, 1)
void lstm_ae_fused(const float* __restrict__ x,
                   const float* __restrict__ eWih, const float* __restrict__ eWhh, const float* __restrict__ eb,
                   const float* __restrict__ lWih, const float* __restrict__ lWhh, const float* __restrict__ lb,
                   const float* __restrict__ dWih, const float* __restrict__ dWhh, const float* __restrict__ db,
                   const float* __restrict__ oW,  const float* __restrict__ ob,
                   float* __restrict__ out)
{
  extern __shared__ char smem[];
  const int tid = threadIdx.x;
  const int j  = tid & 63;
  const int bs = tid >> 6;
  const int b0 = bs * 4;
  const int bbase = blockIdx.x * 16;

  // ---------------- phase 1: encoder ----------------
  float4* sWihE = (float4*)(smem);            // [40][64]
  float4* sWhhE = (float4*)(smem + 40960);    // [64][64]
  float*  xs    = (float*)(smem + 124928);    // [16][40]
  float*  hE    = (float*)(smem + 127488);    // [2][16][64]

  for (int idx = tid; idx < 64 * 64; idx += 256) {
    int k = idx >> 6, u = idx & 63;
    float4 w;
    w.x = eWhh[(u      ) * 64 + k];
    w.y = eWhh[(u +  64) * 64 + k];
    w.z = eWhh[(u + 128) * 64 + k];
    w.w = eWhh[(u + 192) * 64 + k];
    sWhhE[idx] = w;
  }
  for (int idx = tid; idx < 40 * 64; idx += 256) {
    int f = idx >> 6, u = idx & 63;
    float4 w;
    w.x = eWih[(u      ) * 40 + f];
    w.y = eWih[(u +  64) * 40 + f];
    w.z = eWih[(u + 128) * 40 + f];
    w.w = eWih[(u + 192) * 40 + f];
    sWihE[idx] = w;
  }
  for (int idx = tid; idx < 16 * 64; idx += 256) hE[idx] = 0.0f;

  const float4 bE = make_float4(eb[j], eb[64 + j], eb[128 + j], eb[192 + j]);
  float cE0 = 0.f, cE1 = 0.f, cE2 = 0.f, cE3 = 0.f;
  int p = 0;
  __syncthreads();

#pragma unroll 1
  for (int t = 0; t < T_STEPS; ++t) {
    // stage x_t for the block's 16 batch rows
    for (int idx = tid; idx < 160; idx += 256) {
      int b = idx / 10, f4i = idx % 10;
      const float4* src = (const float4*)(x + ((size_t)(bbase + b) * T_STEPS + t) * FEAT);
      ((float4*)xs)[b * 10 + f4i] = src[f4i];
    }
    __syncthreads();

    float4 a0 = bE, a1 = bE, a2 = bE, a3 = bE;
    const float4* xs4 = (const float4*)xs;
    const float4* h4  = (const float4*)(hE + p * 1024);
#pragma unroll
    for (int f4i = 0; f4i < 10; ++f4i) {
      float4 x0 = xs4[(b0 + 0) * 10 + f4i];
      float4 x1 = xs4[(b0 + 1) * 10 + f4i];
      float4 x2 = xs4[(b0 + 2) * 10 + f4i];
      float4 x3 = xs4[(b0 + 3) * 10 + f4i];
#pragma unroll
      for (int e = 0; e < 4; ++e) {
        float4 w = sWihE[(f4i * 4 + e) * 64 + j];
        fma4(a0, w, f4c(x0, e));
        fma4(a1, w, f4c(x1, e));
        fma4(a2, w, f4c(x2, e));
        fma4(a3, w, f4c(x3, e));
      }
    }
#pragma unroll
    for (int k4 = 0; k4 < 16; ++k4) {
      float4 h0 = h4[(b0 + 0) * 16 + k4];
      float4 h1 = h4[(b0 + 1) * 16 + k4];
      float4 h2 = h4[(b0 + 2) * 16 + k4];
      float4 h3 = h4[(b0 + 3) * 16 + k4];
#pragma unroll
      for (int e = 0; e < 4; ++e) {
        float4 w = sWhhE[(k4 * 4 + e) * 64 + j];
        fma4(a0, w, f4c(h0, e));
        fma4(a1, w, f4c(h1, e));
        fma4(a2, w, f4c(h2, e));
        fma4(a3, w, f4c(h3, e));
      }
    }
    float* hw = hE + (p ^ 1) * 1024;
    {
      float ii, ff, gg, oo;
      ii = fast_sig(a0.x); ff = fast_sig(a0.y); gg = fast_tanh(a0.z); oo = fast_sig(a0.w);
      cE0 = ff * cE0 + ii * gg; hw[(b0 + 0) * 64 + j] = oo * fast_tanh(cE0);
      ii = fast_sig(a1.x); ff = fast_sig(a1.y); gg = fast_tanh(a1.z); oo = fast_sig(a1.w);
      cE1 = ff * cE1 + ii * gg; hw[(b0 + 1) * 64 + j] = oo * fast_tanh(cE1);
      ii = fast_sig(a2.x); ff = fast_sig(a2.y); gg = fast_tanh(a2.z); oo = fast_sig(a2.w);
      cE2 = ff * cE2 + ii * gg; hw[(b0 + 2) * 64 + j] = oo * fast_tanh(cE2);
      ii = fast_sig(a3.x); ff = fast_sig(a3.y); gg = fast_tanh(a3.z); oo = fast_sig(a3.w);
      cE3 = ff * cE3 + ii * gg; hw[(b0 + 3) * 64 + j] = oo * fast_tanh(cE3);
    }
    __syncthreads();
    p ^= 1;
  }

  // ---------------- latent input transform (encoder last h is constant input) ----------------
  float4 xg0 = make_float4(0, 0, 0, 0), xg1 = xg0, xg2 = xg0, xg3 = xg0;
  if (j < 32) {
    float4 bL = make_float4(lb[j], lb[32 + j], lb[64 + j], lb[96 + j]);
    xg0 = bL; xg1 = bL; xg2 = bL; xg3 = bL;
    const float* hp = hE + p * 1024;
#pragma unroll 4
    for (int k = 0; k < 64; ++k) {
      float4 w;
      w.x = lWih[(j     ) * 64 + k];
      w.y = lWih[(j + 32) * 64 + k];
      w.z = lWih[(j + 64) * 64 + k];
      w.w = lWih[(j + 96) * 64 + k];
      fma4(xg0, w, hp[(b0 + 0) * 64 + k]);
      fma4(xg1, w, hp[(b0 + 1) * 64 + k]);
      fma4(xg2, w, hp[(b0 + 2) * 64 + k]);
      fma4(xg3, w, hp[(b0 + 3) * 64 + k]);
    }
  }
  __syncthreads();

  // ---------------- phase 2: latent + decoder + projection ----------------
  float4* sWhhD = (float4*)(smem);            // [64][64]
  float4* sWihD = (float4*)(smem + 65536);    // [32][64]
  float4* sWhhL = (float4*)(smem + 98304);    // [32][32]
  float4* sOutW = (float4*)(smem + 114688);   // [16][40]
  float*  hL    = (float*)(smem + 124928);    // [2][16][32]
  float*  hD    = (float*)(smem + 129024);    // [2][16][64]

  for (int idx = tid; idx < 64 * 64; idx += 256) {
    int k = idx >> 6, u = idx & 63;
    float4 w;
    w.x = dWhh[(u      ) * 64 + k];
    w.y = dWhh[(u +  64) * 64 + k];
    w.z = dWhh[(u + 128) * 64 + k];
    w.w = dWhh[(u + 192) * 64 + k];
    sWhhD[idx] = w;
  }
  for (int idx = tid; idx < 32 * 64; idx += 256) {
    int k = idx >> 6, u = idx & 63;
    float4 w;
    w.x = dWih[(u      ) * 32 + k];
    w.y = dWih[(u +  64) * 32 + k];
    w.z = dWih[(u + 128) * 32 + k];
    w.w = dWih[(u + 192) * 32 + k];
    sWihD[idx] = w;
  }
  for (int idx = tid; idx < 32 * 32; idx += 256) {
    int k = idx >> 5, u = idx & 31;
    float4 w;
    w.x = lWhh[(u     ) * 32 + k];
    w.y = lWhh[(u + 32) * 32 + k];
    w.z = lWhh[(u + 64) * 32 + k];
    w.w = lWhh[(u + 96) * 32 + k];
    sWhhL[idx] = w;
  }
  for (int idx = tid; idx < 16 * 40; idx += 256) {
    int k4 = idx / 40, f = idx % 40;
    const float* src = oW + f * 64 + k4 * 4;
    sOutW[idx] = make_float4(src[0], src[1], src[2], src[3]);
  }
  for (int idx = tid; idx < 16 * 32; idx += 256) hL[idx] = 0.0f;
  for (int idx = tid; idx < 16 * 64; idx += 256) hD[idx] = 0.0f;

  const float4 bD = make_float4(db[j], db[64 + j], db[128 + j], db[192 + j]);
  const float obj = (j < 40) ? ob[j] : 0.0f;
  float cL0 = 0, cL1 = 0, cL2 = 0, cL3 = 0;
  float cD0 = 0, cD1 = 0, cD2 = 0, cD3 = 0;
  int q = 0;
  __syncthreads();

#pragma unroll 1
  for (int t = 0; t < T_STEPS; ++t) {
    // --- latent step (lanes j<32) ---
    if (j < 32) {
      float4 l0 = xg0, l1 = xg1, l2 = xg2, l3 = xg3;
      const float4* hl4 = (const float4*)(hL + q * 512);
#pragma unroll
      for (int k4 = 0; k4 < 8; ++k4) {
        float4 h0 = hl4[(b0 + 0) * 8 + k4];
        float4 h1 = hl4[(b0 + 1) * 8 + k4];
        float4 h2 = hl4[(b0 + 2) * 8 + k4];
        float4 h3 = hl4[(b0 + 3) * 8 + k4];
#pragma unroll
        for (int e = 0; e < 4; ++e) {
          float4 w = sWhhL[(k4 * 4 + e) * 32 + j];
          fma4(l0, w, f4c(h0, e));
          fma4(l1, w, f4c(h1, e));
          fma4(l2, w, f4c(h2, e));
          fma4(l3, w, f4c(h3, e));
        }
      }
      float* hlw = hL + (q ^ 1) * 512;
      float ii, ff, gg, oo;
      ii = fast_sig(l0.x); ff = fast_sig(l0.y); gg = fast_tanh(l0.z); oo = fast_sig(l0.w);
      cL0 = ff * cL0 + ii * gg; hlw[(b0 + 0) * 32 + j] = oo * fast_tanh(cL0);
      ii = fast_sig(l1.x); ff = fast_sig(l1.y); gg = fast_tanh(l1.z); oo = fast_sig(l1.w);
      cL1 = ff * cL1 + ii * gg; hlw[(b0 + 1) * 32 + j] = oo * fast_tanh(cL1);
      ii = fast_sig(l2.x); ff = fast_sig(l2.y); gg = fast_tanh(l2.z); oo = fast_sig(l2.w);
      cL2 = ff * cL2 + ii * gg; hlw[(b0 + 2) * 32 + j] = oo * fast_tanh(cL2);
      ii = fast_sig(l3.x); ff = fast_sig(l3.y); gg = fast_tanh(l3.z); oo = fast_sig(l3.w);
      cL3 = ff * cL3 + ii * gg; hlw[(b0 + 3) * 32 + j] = oo * fast_tanh(cL3);
    }
    __syncthreads();

    // --- decoder step (all lanes) ---
    float4 d0 = bD, d1 = bD, d2 = bD, d3 = bD;
    {
      const float4* hl4 = (const float4*)(hL + (q ^ 1) * 512);
#pragma unroll
      for (int k4 = 0; k4 < 8; ++k4) {
        float4 h0 = hl4[(b0 + 0) * 8 + k4];
        float4 h1 = hl4[(b0 + 1) * 8 + k4];
        float4 h2 = hl4[(b0 + 2) * 8 + k4];
        float4 h3 = hl4[(b0 + 3) * 8 + k4];
#pragma unroll
        for (int e = 0; e < 4; ++e) {
          float4 w = sWihD[(k4 * 4 + e) * 64 + j];
          fma4(d0, w, f4c(h0, e));
          fma4(d1, w, f4c(h1, e));
          fma4(d2, w, f4c(h2, e));
          fma4(d3, w, f4c(h3, e));
        }
      }
      const float4* hd4 = (const float4*)(hD + q * 1024);
#pragma unroll
      for (int k4 = 0; k4 < 16; ++k4) {
        float4 h0 = hd4[(b0 + 0) * 16 + k4];
        float4 h1 = hd4[(b0 + 1) * 16 + k4];
        float4 h2 = hd4[(b0 + 2) * 16 + k4];
        float4 h3 = hd4[(b0 + 3) * 16 + k4];
#pragma unroll
        for (int e = 0; e < 4; ++e) {
          float4 w = sWhhD[(k4 * 4 + e) * 64 + j];
          fma4(d0, w, f4c(h0, e));
          fma4(d1, w, f4c(h1, e));
          fma4(d2, w, f4c(h2, e));
          fma4(d3, w, f4c(h3, e));
        }
      }
    }
    float* hdw = hD + (q ^ 1) * 1024;
    {
      float ii, ff, gg, oo;
      ii = fast_sig(d0.x); ff = fast_sig(d0.y); gg = fast_tanh(d0.z); oo = fast_sig(d0.w);
      cD0 = ff * cD0 + ii * gg; hdw[(b0 + 0) * 64 + j] = oo * fast_tanh(cD0);
      ii = fast_sig(d1.x); ff = fast_sig(d1.y); gg = fast_tanh(d1.z); oo = fast_sig(d1.w);
      cD1 = ff * cD1 + ii * gg; hdw[(b0 + 1) * 64 + j] = oo * fast_tanh(cD1);
      ii = fast_sig(d2.x); ff = fast_sig(d2.y); gg = fast_tanh(d2.z); oo = fast_sig(d2.w);
      cD2 = ff * cD2 + ii * gg; hdw[(b0 + 2) * 64 + j] = oo * fast_tanh(cD2);
      ii = fast_sig(d3.x); ff = fast_sig(d3.y); gg = fast_tanh(d3.z); oo = fast_sig(d3.w);
      cD3 = ff * cD3 + ii * gg; hdw[(b0 + 3) * 64 + j] = oo * fast_tanh(cD3);
    }
    __syncthreads();

    // --- output projection (lanes j<40) ---
    if (j < 40) {
      const float4* hd4 = (const float4*)(hD + (q ^ 1) * 1024);
      float o0 = obj, o1 = obj, o2 = obj, o3 = obj;
#pragma unroll
      for (int k4 = 0; k4 < 16; ++k4) {
        float4 w = sOutW[k4 * 40 + j];
        float4 h0 = hd4[(b0 + 0) * 16 + k4];
        float4 h1 = hd4[(b0 + 1) * 16 + k4];
        float4 h2 = hd4[(b0 + 2) * 16 + k4];
        float4 h3 = hd4[(b0 + 3) * 16 + k4];
        o0 = fmaf(w.x, h0.x, fmaf(w.y, h0.y, fmaf(w.z, h0.z, fmaf(w.w, h0.w, o0))));
        o1 = fmaf(w.x, h1.x, fmaf(w.y, h1.y, fmaf(w.z, h1.z, fmaf(w.w, h1.w, o1))));
        o2 = fmaf(w.x, h2.x, fmaf(w.y, h2.y, fmaf(w.z, h2.z, fmaf(w.w, h2.w, o2))));
        o3 = fmaf(w.x, h3.x, fmaf(w.y, h3.y, fmaf(w.z, h3.z, fmaf(w.w, h3.w, o3))));
      }
      size_t o = ((size_t)(bbase + b0) * T_STEPS + t) * FEAT + j;
      const size_t bstride = (size_t)T_STEPS * FEAT;
      out[o]               = o0;
      out[o + bstride]     = o1;
      out[o + 2 * bstride] = o2;
      out[o + 3 * bstride] = o3;
    }
    q ^= 1;
  }
}

extern "C" void kernel_launch(void* const* d_in, const int* in_sizes, int n_in,
                              void* d_out, int out_size, void* d_ws, size_t ws_size,
                              hipStream_t stream) {
  const float* x    = (const float*)d_in[0];
  const float* eWih = (const float*)d_in[1];
  const float* eWhh = (const float*)d_in[2];
  const float* eb   = (const float*)d_in[3];
  const float* lWih = (const float*)d_in[4];
  const float* lWhh = (const float*)d_in[5];
  const float* lb   = (const float*)d_in[6];
  const float* dWih = (const float*)d_in[7];
  const float* dWhh = (const float*)d_in[8];
  const float* db   = (const float*)d_in[9];
  const float* oW   = (const float*)d_in[10];
  const float* ob   = (const float*)d_in[11];
  float* out = (float*)d_out;

  (void)hipFuncSetAttribute((const void*)lstm_ae_fused,
                            hipFuncAttributeMaxDynamicSharedMemorySize, SMEM_BYTES);
  lstm_ae_fused<<<256, 256, SMEM_BYTES, stream>>>(x, eWih, eWhh, eb, lWih, lWhh, lb,
                                                  dWih, dWhh, db, oW, ob, out);
}

// Round 2
// 312.635 us; speedup vs baseline: 3.8411x; 3.8411x over previous
//
#include <hip/hip_runtime.h>
#include <cstddef>

typedef __attribute__((ext_vector_type(8))) short bf16x8;
typedef __attribute__((ext_vector_type(4))) float f32x4;

#define MFMA(a, b, c) __builtin_amdgcn_mfma_f32_16x16x32_bf16((a), (b), (c), 0, 0, 0)

static __device__ __forceinline__ unsigned short f2bf(float f) {
  unsigned u = __builtin_bit_cast(unsigned, f);
  u = u + 0x7FFFu + ((u >> 16) & 1u);
  return (unsigned short)(u >> 16);
}
static __device__ __forceinline__ float bf2f(unsigned short h) {
  unsigned u = ((unsigned)h) << 16;
  return __builtin_bit_cast(float, u);
}
static __device__ __forceinline__ float fast_sig(float x) {
  return __builtin_amdgcn_rcpf(1.0f + __expf(-x));
}
static __device__ __forceinline__ float fast_tanh(float x) {
  return 2.0f * __builtin_amdgcn_rcpf(1.0f + __expf(-2.0f * x)) - 1.0f;
}

// A-buffer: [16 rows (batch)][256 B = 128 bf16 k-slots], XOR-swizzled row bytes.
// A-fragment: lane holds row b=lane&15, k = kc*32 + (lane>>4)*8 + {0..7}.
static __device__ __forceinline__ bf16x8 aread(const char* base, int lane, int kc) {
  int b = lane & 15, g = lane >> 4;
  int off = (kc * 64 + g * 16) ^ ((b & 7) << 4);
  return *(const bf16x8*)(base + b * 256 + off);
}
static __device__ __forceinline__ void awrite16(char* base, int b, int k, unsigned short v) {
  int off = (2 * k) ^ ((b & 7) << 4);
  *(unsigned short*)(base + b * 256 + off) = (unsigned short)v;
}

extern "C" __global__ __launch_bounds__(256, 1)
void lstm_ae_mfma(const float* __restrict__ x,
                  const float* __restrict__ eWih, const float* __restrict__ eWhh, const float* __restrict__ eb,
                  const float* __restrict__ lWih, const float* __restrict__ lWhh, const float* __restrict__ lb,
                  const float* __restrict__ dWih, const float* __restrict__ dWhh, const float* __restrict__ db,
                  const float* __restrict__ oW,  const float* __restrict__ ob,
                  float* __restrict__ out)
{
  __shared__ __align__(16) char sAhi[2][4096];   // A hi, double-buffered
  __shared__ __align__(16) char sAlo[2][4096];   // A lo
  __shared__ __align__(16) float sG[16 * 256];   // gates [b][ghat] f32

  const int tid  = threadIdx.x;
  const int lane = tid & 63;
  const int w    = tid >> 6;       // wave id 0..3
  const int c16  = lane & 15;      // MFMA col / A-row lane field
  const int p4   = lane >> 4;      // lane group
  const int bbase = blockIdx.x * 16;

  // ---------- zero A buffers ----------
  {
    f32x4 z = {0.f, 0.f, 0.f, 0.f};
#pragma unroll
    for (int i = 0; i < 2; ++i) {
      int off = tid * 16 + i * 4096;
      *(f32x4*)(&sAhi[0][0] + off) = z;
      *(f32x4*)(&sAlo[0][0] + off) = z;
    }
  }

  // ---------- stage x_0 into buf 0 ----------
  if (tid < 160) {
    int b = tid / 10, f4 = tid - b * 10;
    f32x4 ld = *(const f32x4*)(x + ((size_t)(bbase + b) * 100 + 0) * 40 + f4 * 4);
    unsigned long long ph = 0, pl = 0;
#pragma unroll
    for (int e = 0; e < 4; ++e) {
      unsigned short hh = f2bf(ld[e]);
      unsigned short ll = f2bf(ld[e] - bf2f(hh));
      ph |= ((unsigned long long)hh) << (16 * e);
      pl |= ((unsigned long long)ll) << (16 * e);
    }
    int off = (f4 * 8) ^ ((b & 7) << 4);
    *(unsigned long long*)(sAhi[0] + b * 256 + off) = ph;
    *(unsigned long long*)(sAlo[0] + b * 256 + off) = pl;
  }

  int q = 0;

  // ================= PHASE 1: encoder =================
  // K layout: k 0..39 = x_t, 40..63 = zero pad, 64..127 = h_enc(t-1). 4 k-chunks.
  {
    bf16x8 eBh[4][4], eBl[4][4];
    float ebias[4];
#pragma unroll
    for (int n = 0; n < 4; ++n) {
      int col = w * 64 + n * 16 + c16;      // ghat = unit*4 + gate
      int u = col >> 2, ga = col & 3;       // PyTorch rows: gate-major ga*64+u
      ebias[n] = eb[ga * 64 + u];
#pragma unroll
      for (int kc = 0; kc < 4; ++kc) {
        bf16x8 hi, lo;
#pragma unroll
        for (int e = 0; e < 8; ++e) {
          int k = kc * 32 + p4 * 8 + e;
          float v = 0.0f;
          if (k < 40)       v = eWih[(ga * 64 + u) * 40 + k];
          else if (k >= 64) v = eWhh[(ga * 64 + u) * 64 + (k - 64)];
          unsigned short hh = f2bf(v);
          hi[e] = (short)hh;
          lo[e] = (short)f2bf(v - bf2f(hh));
        }
        eBh[n][kc] = hi; eBl[n][kc] = lo;
      }
    }

    float cE[4] = {0.f, 0.f, 0.f, 0.f};
    __syncthreads();

#pragma unroll 1
    for (int t = 0; t < 100; ++t) {
      f32x4 acc[4];
#pragma unroll
      for (int n = 0; n < 4; ++n) acc[n] = f32x4{ebias[n], ebias[n], ebias[n], ebias[n]};
      const char* Ah = sAhi[q];
      const char* Al = sAlo[q];
#pragma unroll
      for (int kc = 0; kc < 4; ++kc) {
        bf16x8 ah = aread(Ah, lane, kc);
        bf16x8 al = aread(Al, lane, kc);
#pragma unroll
        for (int n = 0; n < 4; ++n) {
          acc[n] = MFMA(ah, eBh[n][kc], acc[n]);
          acc[n] = MFMA(al, eBh[n][kc], acc[n]);
          acc[n] = MFMA(ah, eBl[n][kc], acc[n]);
        }
      }
      // gate scatter: sG[b][ghat], C/D rows = batch
#pragma unroll
      for (int n = 0; n < 4; ++n) {
        int col = w * 64 + n * 16 + c16;
#pragma unroll
        for (int r = 0; r < 4; ++r) sG[(p4 * 4 + r) * 256 + col] = acc[n][r];
      }
      __syncthreads();

      // h producers: unit u = lane, batches 4w..4w+3
      char* AhN = sAhi[q ^ 1];
      char* AlN = sAlo[q ^ 1];
#pragma unroll
      for (int r = 0; r < 4; ++r) {
        int b = 4 * w + r;
        f32x4 gv = *(const f32x4*)(sG + b * 256 + 4 * lane);
        float ii = fast_sig(gv[0]), ff = fast_sig(gv[1]);
        float gg = fast_tanh(gv[2]), oo = fast_sig(gv[3]);
        cE[r] = ff * cE[r] + ii * gg;
        float hv = oo * fast_tanh(cE[r]);
        unsigned short hh = f2bf(hv);
        awrite16(AhN, b, 64 + lane, hh);
        awrite16(AlN, b, 64 + lane, f2bf(hv - bf2f(hh)));
      }
      // stage x_{t+1}
      if (tid < 160) {
        int tn = (t + 1 < 100) ? t + 1 : 99;
        int b = tid / 10, f4 = tid - b * 10;
        f32x4 ld = *(const f32x4*)(x + ((size_t)(bbase + b) * 100 + tn) * 40 + f4 * 4);
        unsigned long long ph = 0, pl = 0;
#pragma unroll
        for (int e = 0; e < 4; ++e) {
          unsigned short hh = f2bf(ld[e]);
          unsigned short ll = f2bf(ld[e] - bf2f(hh));
          ph |= ((unsigned long long)hh) << (16 * e);
          pl |= ((unsigned long long)ll) << (16 * e);
        }
        int off = (f4 * 8) ^ ((b & 7) << 4);
        *(unsigned long long*)(AhN + b * 256 + off) = ph;
        *(unsigned long long*)(AlN + b * 256 + off) = pl;
      }
      __syncthreads();
      q ^= 1;
    }
  }

  // ================= xg = lb + h_enc_last @ lWih^T (one shot) =================
  // h_enc_last sits in sA*[q] k-slots 64..127 (chunks 2,3).
  f32x4 xga[2];
  {
    bf16x8 gBh[2][2], gBl[2][2];
    float gbias[2];
#pragma unroll
    for (int n = 0; n < 2; ++n) {
      int col = w * 32 + n * 16 + c16;      // latent ghat 0..127
      int u = col >> 2, ga = col & 3;
      gbias[n] = lb[ga * 32 + u];
#pragma unroll
      for (int kci = 0; kci < 2; ++kci) {
        bf16x8 hi, lo;
#pragma unroll
        for (int e = 0; e < 8; ++e) {
          int he = kci * 32 + p4 * 8 + e;   // 0..63
          float v = lWih[(ga * 32 + u) * 64 + he];
          unsigned short hh = f2bf(v);
          hi[e] = (short)hh;
          lo[e] = (short)f2bf(v - bf2f(hh));
        }
        gBh[n][kci] = hi; gBl[n][kci] = lo;
      }
    }
#pragma unroll
    for (int n = 0; n < 2; ++n) xga[n] = f32x4{gbias[n], gbias[n], gbias[n], gbias[n]};
    const char* Ah = sAhi[q];
    const char* Al = sAlo[q];
#pragma unroll
    for (int kci = 0; kci < 2; ++kci) {
      bf16x8 ah = aread(Ah, lane, 2 + kci);
      bf16x8 al = aread(Al, lane, 2 + kci);
#pragma unroll
      for (int n = 0; n < 2; ++n) {
        xga[n] = MFMA(ah, gBh[n][kci], xga[n]);
        xga[n] = MFMA(al, gBh[n][kci], xga[n]);
        xga[n] = MFMA(ah, gBl[n][kci], xga[n]);
      }
    }
  }
  __syncthreads();

  // re-zero A buffers (h_lat(0) = h_dec(0) = 0)
  {
    f32x4 z = {0.f, 0.f, 0.f, 0.f};
#pragma unroll
    for (int i = 0; i < 2; ++i) {
      int off = tid * 16 + i * 4096;
      *(f32x4*)(&sAhi[0][0] + off) = z;
      *(f32x4*)(&sAlo[0][0] + off) = z;
    }
  }

  // ================= PHASE 2: latent + decoder + projection =================
  // A k-layout: 0..31 = h_lat, 32..95 = h_dec (3 chunks used).
  {
    bf16x8 lBh[2], lBl[2];                  // latent Whh, 1 k-chunk, 2 n-frags
#pragma unroll
    for (int n = 0; n < 2; ++n) {
      int col = w * 32 + n * 16 + c16;
      int u = col >> 2, ga = col & 3;
      bf16x8 hi, lo;
#pragma unroll
      for (int e = 0; e < 8; ++e) {
        int k = p4 * 8 + e;                 // 0..31
        float v = lWhh[(ga * 32 + u) * 32 + k];
        unsigned short hh = f2bf(v);
        hi[e] = (short)hh;
        lo[e] = (short)f2bf(v - bf2f(hh));
      }
      lBh[n] = hi; lBl[n] = lo;
    }

    bf16x8 dBh[3][4], dBl[3][4];
    float dbias[4];
#pragma unroll
    for (int n = 0; n < 4; ++n) {
      int col = w * 64 + n * 16 + c16;
      int u = col >> 2, ga = col & 3;
      dbias[n] = db[ga * 64 + u];
#pragma unroll
      for (int kc = 0; kc < 3; ++kc) {
        bf16x8 hi, lo;
#pragma unroll
        for (int e = 0; e < 8; ++e) {
          int k = kc * 32 + p4 * 8 + e;     // 0..95
          float v = (k < 32) ? dWih[(ga * 64 + u) * 32 + k]
                             : dWhh[(ga * 64 + u) * 64 + (k - 32)];
          unsigned short hh = f2bf(v);
          hi[e] = (short)hh;
          lo[e] = (short)f2bf(v - bf2f(hh));
        }
        dBh[kc][n] = hi; dBl[kc][n] = lo;
      }
    }

    bf16x8 pBh[2], pBl[2];                  // projection, k-chunks 1,2 (h_dec)
    float obias;
    {
      int f = w * 16 + c16;                 // output feature (pad to 64)
      obias = (f < 40) ? ob[f] : 0.0f;
#pragma unroll
      for (int kci = 0; kci < 2; ++kci) {
        bf16x8 hi, lo;
#pragma unroll
        for (int e = 0; e < 8; ++e) {
          int hd = kci * 32 + p4 * 8 + e;   // 0..63
          float v = (f < 40) ? oW[f * 64 + hd] : 0.0f;
          unsigned short hh = f2bf(v);
          hi[e] = (short)hh;
          lo[e] = (short)f2bf(v - bf2f(hh));
        }
        pBh[kci] = hi; pBl[kci] = lo;
      }
    }

    float cL[2] = {0.f, 0.f};
    float cD[4] = {0.f, 0.f, 0.f, 0.f};
    const int lu = tid & 31;                // latent producer: unit
    const int lq = tid >> 5;                // latent producer: batch pair 0..7
    const int fcol = w * 16 + c16;
    __syncthreads();

#pragma unroll 1
    for (int t = 0; t < 100; ++t) {
      // --- latent recurrent MFMA: A chunk0 of buf q = h_lat(t-1) ---
      f32x4 lac[2];
#pragma unroll
      for (int n = 0; n < 2; ++n) lac[n] = xga[n];
      {
        bf16x8 ah = aread(sAhi[q], lane, 0);
        bf16x8 al = aread(sAlo[q], lane, 0);
#pragma unroll
        for (int n = 0; n < 2; ++n) {
          lac[n] = MFMA(ah, lBh[n], lac[n]);
          lac[n] = MFMA(al, lBh[n], lac[n]);
          lac[n] = MFMA(ah, lBl[n], lac[n]);
        }
      }
#pragma unroll
      for (int n = 0; n < 2; ++n) {
        int col = w * 32 + n * 16 + c16;
#pragma unroll
        for (int r = 0; r < 4; ++r) sG[(p4 * 4 + r) * 256 + col] = lac[n][r];
      }
      __syncthreads();                       // B1

      // --- latent producers: (u=lu, b=2lq+{0,1}) -> h_lat(t) into buf q^1 k 0..31
#pragma unroll
      for (int s = 0; s < 2; ++s) {
        int b = 2 * lq + s;
        f32x4 gv = *(const f32x4*)(sG + b * 256 + 4 * lu);
        float ii = fast_sig(gv[0]), ff = fast_sig(gv[1]);
        float gg = fast_tanh(gv[2]), oo = fast_sig(gv[3]);
        cL[s] = ff * cL[s] + ii * gg;
        float hv = oo * fast_tanh(cL[s]);
        unsigned short hh = f2bf(hv);
        awrite16(sAhi[q ^ 1], b, lu, hh);
        awrite16(sAlo[q ^ 1], b, lu, f2bf(hv - bf2f(hh)));
      }
      __syncthreads();                       // B2

      // --- decoder MFMA: chunk0 from buf q^1 (h_lat(t)), chunks1,2 from buf q (h_dec(t-1))
      f32x4 dac[4];
#pragma unroll
      for (int n = 0; n < 4; ++n) dac[n] = f32x4{dbias[n], dbias[n], dbias[n], dbias[n]};
      {
        bf16x8 ah = aread(sAhi[q ^ 1], lane, 0);
        bf16x8 al = aread(sAlo[q ^ 1], lane, 0);
#pragma unroll
        for (int n = 0; n < 4; ++n) {
          dac[n] = MFMA(ah, dBh[0][n], dac[n]);
          dac[n] = MFMA(al, dBh[0][n], dac[n]);
          dac[n] = MFMA(ah, dBl[0][n], dac[n]);
        }
#pragma unroll
        for (int kc = 1; kc < 3; ++kc) {
          ah = aread(sAhi[q], lane, kc);
          al = aread(sAlo[q], lane, kc);
#pragma unroll
          for (int n = 0; n < 4; ++n) {
            dac[n] = MFMA(ah, dBh[kc][n], dac[n]);
            dac[n] = MFMA(al, dBh[kc][n], dac[n]);
            dac[n] = MFMA(ah, dBl[kc][n], dac[n]);
          }
        }
      }
#pragma unroll
      for (int n = 0; n < 4; ++n) {
        int col = w * 64 + n * 16 + c16;
#pragma unroll
        for (int r = 0; r < 4; ++r) sG[(p4 * 4 + r) * 256 + col] = dac[n][r];
      }
      __syncthreads();                       // B3

      // --- decoder producers: u=lane, b=4w+r -> h_dec(t) into buf q^1 k 32..95
#pragma unroll
      for (int r = 0; r < 4; ++r) {
        int b = 4 * w + r;
        f32x4 gv = *(const f32x4*)(sG + b * 256 + 4 * lane);
        float ii = fast_sig(gv[0]), ff = fast_sig(gv[1]);
        float gg = fast_tanh(gv[2]), oo = fast_sig(gv[3]);
        cD[r] = ff * cD[r] + ii * gg;
        float hv = oo * fast_tanh(cD[r]);
        unsigned short hh = f2bf(hv);
        awrite16(sAhi[q ^ 1], b, 32 + lane, hh);
        awrite16(sAlo[q ^ 1], b, 32 + lane, f2bf(hv - bf2f(hh)));
      }
      __syncthreads();                       // B4

      // --- projection: A chunks 1,2 of buf q^1 (h_dec(t)) ---
      f32x4 pac = f32x4{obias, obias, obias, obias};
#pragma unroll
      for (int kci = 0; kci < 2; ++kci) {
        bf16x8 ah = aread(sAhi[q ^ 1], lane, 1 + kci);
        bf16x8 al = aread(sAlo[q ^ 1], lane, 1 + kci);
        pac = MFMA(ah, pBh[kci], pac);
        pac = MFMA(al, pBh[kci], pac);
        pac = MFMA(ah, pBl[kci], pac);
      }
      if (fcol < 40) {
#pragma unroll
        for (int r = 0; r < 4; ++r) {
          int b = p4 * 4 + r;
          out[((size_t)(bbase + b) * 100 + t) * 40 + fcol] = pac[r];
        }
      }
      q ^= 1;
    }
  }
}

extern "C" void kernel_launch(void* const* d_in, const int* in_sizes, int n_in,
                              void* d_out, int out_size, void* d_ws, size_t ws_size,
                              hipStream_t stream) {
  const float* x    = (const float*)d_in[0];
  const float* eWih = (const float*)d_in[1];
  const float* eWhh = (const float*)d_in[2];
  const float* eb   = (const float*)d_in[3];
  const float* lWih = (const float*)d_in[4];
  const float* lWhh = (const float*)d_in[5];
  const float* lb   = (const float*)d_in[6];
  const float* dWih = (const float*)d_in[7];
  const float* dWhh = (const float*)d_in[8];
  const float* db   = (const float*)d_in[9];
  const float* oW   = (const float*)d_in[10];
  const float* ob   = (const float*)d_in[11];
  float* out = (float*)d_out;

  lstm_ae_mfma<<<256, 256, 0, stream>>>(x, eWih, eWhh, eb, lWih, lWhh, lb,
                                        dWih, dWhh, db, oW, ob, out);
}

// Round 3
// 202.683 us; speedup vs baseline: 5.9249x; 1.5425x over previous
//
#include <hip/hip_runtime.h>
#include <cstddef>

typedef __attribute__((ext_vector_type(8))) short bf16x8;
typedef __attribute__((ext_vector_type(4))) float f32x4;

#define MFMA(a, b, c) __builtin_amdgcn_mfma_f32_16x16x32_bf16((a), (b), (c), 0, 0, 0)

static __device__ __forceinline__ unsigned short f2bf(float f) {
  unsigned u = __builtin_bit_cast(unsigned, f);
  u = u + 0x7FFFu + ((u >> 16) & 1u);
  return (unsigned short)(u >> 16);
}
static __device__ __forceinline__ float bf2f(unsigned short h) {
  unsigned u = ((unsigned)h) << 16;
  return __builtin_bit_cast(float, u);
}
static __device__ __forceinline__ float fast_sig(float x) {
  return __builtin_amdgcn_rcpf(1.0f + __expf(-x));
}
static __device__ __forceinline__ float fast_tanh(float x) {
  return 2.0f * __builtin_amdgcn_rcpf(1.0f + __expf(-2.0f * x)) - 1.0f;
}

// Activation buffer: [16 batch rows][256 B = 128 bf16 k-slots], XOR-swizzled.
// B-fragment (N=batch cols): lane holds col b=lane&15, k = kc*32 + (lane>>4)*8 + {0..7}.
static __device__ __forceinline__ bf16x8 aread(const char* base, int lane, int kc) {
  int b = lane & 15, g = lane >> 4;
  int off = (kc * 64 + g * 16) ^ ((b & 7) << 4);
  return *(const bf16x8*)(base + b * 256 + off);
}
static __device__ __forceinline__ void awrite16(char* base, int b, int k, unsigned short v) {
  int off = (2 * k) ^ ((b & 7) << 4);
  *(unsigned short*)(base + b * 256 + off) = v;
}

// 8 waves (512 thr). Weights = MFMA A-operand (row = ghat = 4*unit+gate), held in VGPRs.
// Activations = B-operand (col = batch) in LDS. C/D: lane c16 = batch, rows p4*4+r = ghat
// -> each lane natively holds all 4 gates (r) of one unit for one batch: in-register LSTM cell,
// no gate LDS round-trip, 1 barrier/step (enc), 2 barriers/step (lat+dec+proj).
extern "C" __global__ __launch_bounds__(512, 2)
void lstm_ae_mfma2(const float* __restrict__ x,
                   const float* __restrict__ eWih, const float* __restrict__ eWhh, const float* __restrict__ eb,
                   const float* __restrict__ lWih, const float* __restrict__ lWhh, const float* __restrict__ lb,
                   const float* __restrict__ dWih, const float* __restrict__ dWhh, const float* __restrict__ db,
                   const float* __restrict__ oW,  const float* __restrict__ ob,
                   float* __restrict__ out)
{
  __shared__ __align__(16) char sAhi[2][4096];
  __shared__ __align__(16) char sAlo[2][4096];

  const int tid  = threadIdx.x;
  const int lane = tid & 63;
  const int w    = tid >> 6;        // wave 0..7
  const int c16  = lane & 15;       // batch (C/D col; B-frag col)
  const int p4   = lane >> 4;
  const int bbase = blockIdx.x * 16;

  // ---------- zero both A buffers (512*16 B = 8 KB = exactly both) ----------
  {
    f32x4 z = {0.f, 0.f, 0.f, 0.f};
    *(f32x4*)(&sAhi[0][0] + tid * 16) = z;
    *(f32x4*)(&sAlo[0][0] + tid * 16) = z;
  }

  // ---------- encoder weights: A-frags, rows = ghat 0..255, k: 0..39 x, 64..127 h ----------
  bf16x8 ewh[2][4], ewl[2][4];
  float ebias[2][4];
#pragma unroll
  for (int n = 0; n < 2; ++n) {
    int row = w * 32 + n * 16 + c16;
    int u = row >> 2, ga = row & 3;
#pragma unroll
    for (int r = 0; r < 4; ++r) ebias[n][r] = eb[r * 64 + (w * 8 + n * 4 + p4)];
#pragma unroll
    for (int kc = 0; kc < 4; ++kc) {
      bf16x8 hi, lo;
#pragma unroll
      for (int e = 0; e < 8; ++e) {
        int k = kc * 32 + p4 * 8 + e;
        float v = 0.f;
        if (k < 40)       v = eWih[(ga * 64 + u) * 40 + k];
        else if (k >= 64) v = eWhh[(ga * 64 + u) * 64 + (k - 64)];
        unsigned short hh = f2bf(v);
        hi[e] = (short)hh;
        lo[e] = (short)f2bf(v - bf2f(hh));
      }
      ewh[n][kc] = hi; ewl[n][kc] = lo;
    }
  }

  __syncthreads();  // zeros visible

  // ---------- stage x_0 into buf 0 ----------
  if (tid < 160) {
    int b = tid / 10, f4 = tid - b * 10;
    f32x4 ld = *(const f32x4*)(x + ((size_t)(bbase + b) * 100 + 0) * 40 + f4 * 4);
    unsigned long long ph = 0, pl = 0;
#pragma unroll
    for (int e = 0; e < 4; ++e) {
      unsigned short hh = f2bf(ld[e]);
      unsigned short ll = f2bf(ld[e] - bf2f(hh));
      ph |= (unsigned long long)hh << (16 * e);
      pl |= (unsigned long long)ll << (16 * e);
    }
    int off = (f4 * 8) ^ ((b & 7) << 4);
    *(unsigned long long*)(sAhi[0] + b * 256 + off) = ph;
    *(unsigned long long*)(sAlo[0] + b * 256 + off) = pl;
  }

  float cE[2] = {0.f, 0.f};
  int q = 0;
  __syncthreads();

  // ================= PHASE 1: encoder, 1 barrier/step =================
#pragma unroll 1
  for (int t = 0; t < 100; ++t) {
    // prefetch x_{t+1} (written to q^1 after compute)
    f32x4 xld;
    int sb = 0, sf4 = 0;
    const bool stager = (tid < 160);
    if (stager) {
      int tn = (t + 1 < 100) ? t + 1 : 99;
      sb = tid / 10; sf4 = tid - sb * 10;
      xld = *(const f32x4*)(x + ((size_t)(bbase + sb) * 100 + tn) * 40 + sf4 * 4);
    }

    f32x4 acc[2];
#pragma unroll
    for (int n = 0; n < 2; ++n)
      acc[n] = f32x4{ebias[n][0], ebias[n][1], ebias[n][2], ebias[n][3]};
    const char* Ah = sAhi[q];
    const char* Al = sAlo[q];
#pragma unroll
    for (int kc = 0; kc < 4; ++kc) {
      bf16x8 ah = aread(Ah, lane, kc);
      bf16x8 al = aread(Al, lane, kc);
#pragma unroll
      for (int n = 0; n < 2; ++n) {
        acc[n] = MFMA(ewh[n][kc], ah, acc[n]);
        acc[n] = MFMA(ewl[n][kc], ah, acc[n]);
        acc[n] = MFMA(ewh[n][kc], al, acc[n]);
      }
    }

    char* AhN = sAhi[q ^ 1];
    char* AlN = sAlo[q ^ 1];
#pragma unroll
    for (int n = 0; n < 2; ++n) {   // in-register cell update: gates = acc[n][0..3]
      float ii = fast_sig(acc[n][0]), ff = fast_sig(acc[n][1]);
      float gg = fast_tanh(acc[n][2]), oo = fast_sig(acc[n][3]);
      cE[n] = ff * cE[n] + ii * gg;
      float hv = oo * fast_tanh(cE[n]);
      unsigned short hh = f2bf(hv);
      int k = 64 + w * 8 + n * 4 + p4;
      awrite16(AhN, c16, k, hh);
      awrite16(AlN, c16, k, f2bf(hv - bf2f(hh)));
    }
    if (stager) {
      unsigned long long ph = 0, pl = 0;
#pragma unroll
      for (int e = 0; e < 4; ++e) {
        unsigned short hh = f2bf(xld[e]);
        unsigned short ll = f2bf(xld[e] - bf2f(hh));
        ph |= (unsigned long long)hh << (16 * e);
        pl |= (unsigned long long)ll << (16 * e);
      }
      int off = (sf4 * 8) ^ ((sb & 7) << 4);
      *(unsigned long long*)(AhN + sb * 256 + off) = ph;
      *(unsigned long long*)(AlN + sb * 256 + off) = pl;
    }
    __syncthreads();
    q ^= 1;
  }

  // ================= xg = lb + lWih @ h_enc_last (rows = latent ghat 0..127) =================
  f32x4 xga;
  {
    int row = w * 16 + c16;
    int u = row >> 2, ga = row & 3;
    int ul = w * 4 + p4;
    xga = f32x4{lb[ul], lb[32 + ul], lb[64 + ul], lb[96 + ul]};
#pragma unroll
    for (int kci = 0; kci < 2; ++kci) {
      bf16x8 hi, lo;
#pragma unroll
      for (int e = 0; e < 8; ++e) {
        float v = lWih[(ga * 32 + u) * 64 + kci * 32 + p4 * 8 + e];
        unsigned short hh = f2bf(v);
        hi[e] = (short)hh;
        lo[e] = (short)f2bf(v - bf2f(hh));
      }
      bf16x8 ah = aread(sAhi[q], lane, 2 + kci);
      bf16x8 al = aread(sAlo[q], lane, 2 + kci);
      xga = MFMA(hi, ah, xga);
      xga = MFMA(lo, ah, xga);
      xga = MFMA(hi, al, xga);
    }
  }
  __syncthreads();  // done reading h_enc

  // re-zero both buffers (h_lat(0) = h_dec(0) = 0)
  {
    f32x4 z = {0.f, 0.f, 0.f, 0.f};
    *(f32x4*)(&sAhi[0][0] + tid * 16) = z;
    *(f32x4*)(&sAlo[0][0] + tid * 16) = z;
  }

  // ---------- phase-2 weights ----------
  // latent Whh: rows = latent ghat (1 frag/wave), k 0..31 = h_lat
  bf16x8 lwh, lwl;
  {
    int row = w * 16 + c16;
    int u = row >> 2, ga = row & 3;
    bf16x8 hi, lo;
#pragma unroll
    for (int e = 0; e < 8; ++e) {
      float v = lWhh[(ga * 32 + u) * 32 + p4 * 8 + e];
      unsigned short hh = f2bf(v);
      hi[e] = (short)hh;
      lo[e] = (short)f2bf(v - bf2f(hh));
    }
    lwh = hi; lwl = lo;
  }
  // decoder: rows = dec ghat (2 frags/wave), k: 0..31 h_lat (Wih), 32..95 h_dec (Whh)
  bf16x8 dwh[2][3], dwl[2][3];
  float dbias[2][4];
#pragma unroll
  for (int n = 0; n < 2; ++n) {
    int row = w * 32 + n * 16 + c16;
    int u = row >> 2, ga = row & 3;
#pragma unroll
    for (int r = 0; r < 4; ++r) dbias[n][r] = db[r * 64 + (w * 8 + n * 4 + p4)];
#pragma unroll
    for (int kc = 0; kc < 3; ++kc) {
      bf16x8 hi, lo;
#pragma unroll
      for (int e = 0; e < 8; ++e) {
        int k = kc * 32 + p4 * 8 + e;
        float v = (k < 32) ? dWih[(ga * 64 + u) * 32 + k]
                           : dWhh[(ga * 64 + u) * 64 + (k - 32)];
        unsigned short hh = f2bf(v);
        hi[e] = (short)hh;
        lo[e] = (short)f2bf(v - bf2f(hh));
      }
      dwh[n][kc] = hi; dwl[n][kc] = lo;
    }
  }
  // projection: rows = feature f (waves 0..2), k chunks 1,2 = h_dec 0..63
  bf16x8 pwh[2], pwl[2];
  float pbias[4];
#pragma unroll
  for (int r = 0; r < 4; ++r) {
    int f = w * 16 + p4 * 4 + r;
    pbias[r] = (w < 3 && f < 40) ? ob[f] : 0.0f;
  }
  if (w < 3) {
    int f = w * 16 + c16;
#pragma unroll
    for (int kci = 0; kci < 2; ++kci) {
      bf16x8 hi, lo;
#pragma unroll
      for (int e = 0; e < 8; ++e) {
        float v = (f < 40) ? oW[f * 64 + kci * 32 + p4 * 8 + e] : 0.0f;
        unsigned short hh = f2bf(v);
        hi[e] = (short)hh;
        lo[e] = (short)f2bf(v - bf2f(hh));
      }
      pwh[kci] = hi; pwl[kci] = lo;
    }
  }

  float cL = 0.f;
  float cD[2] = {0.f, 0.f};
  q = 0;
  __syncthreads();

  // ================= PHASE 2: latent + decoder + projection, 2 barriers/step =================
  // buf k-layout: 0..31 h_lat, 32..95 h_dec
#pragma unroll 1
  for (int t = 0; t < 100; ++t) {
    // --- slot A: reads buf q ---
    bf16x8 l0h = aread(sAhi[q], lane, 0), l0l = aread(sAlo[q], lane, 0);
    bf16x8 d1h = aread(sAhi[q], lane, 1), d1l = aread(sAlo[q], lane, 1);
    bf16x8 d2h = aread(sAhi[q], lane, 2), d2l = aread(sAlo[q], lane, 2);

    // latent gates
    f32x4 lac = xga;
    lac = MFMA(lwh, l0h, lac);
    lac = MFMA(lwl, l0h, lac);
    lac = MFMA(lwh, l0l, lac);

    // decoder Whh partial (h_dec(t-1))
    f32x4 dac[2];
#pragma unroll
    for (int n = 0; n < 2; ++n) {
      dac[n] = f32x4{dbias[n][0], dbias[n][1], dbias[n][2], dbias[n][3]};
      dac[n] = MFMA(dwh[n][1], d1h, dac[n]);
      dac[n] = MFMA(dwl[n][1], d1h, dac[n]);
      dac[n] = MFMA(dwh[n][1], d1l, dac[n]);
      dac[n] = MFMA(dwh[n][2], d2h, dac[n]);
      dac[n] = MFMA(dwl[n][2], d2h, dac[n]);
      dac[n] = MFMA(dwh[n][2], d2l, dac[n]);
    }

    // projection of step t-1 (shares d1/d2 reads)
    if (t > 0 && w < 3) {
      f32x4 pac = f32x4{pbias[0], pbias[1], pbias[2], pbias[3]};
      pac = MFMA(pwh[0], d1h, pac);
      pac = MFMA(pwl[0], d1h, pac);
      pac = MFMA(pwh[0], d1l, pac);
      pac = MFMA(pwh[1], d2h, pac);
      pac = MFMA(pwl[1], d2h, pac);
      pac = MFMA(pwh[1], d2l, pac);
#pragma unroll
      for (int r = 0; r < 4; ++r) {
        int f = w * 16 + p4 * 4 + r;
        if (f < 40)
          out[((size_t)(bbase + c16) * 100 + (t - 1)) * 40 + f] = pac[r];
      }
    }

    // latent cell update + h_lat(t) write
    {
      float ii = fast_sig(lac[0]), ff = fast_sig(lac[1]);
      float gg = fast_tanh(lac[2]), oo = fast_sig(lac[3]);
      cL = ff * cL + ii * gg;
      float hv = oo * fast_tanh(cL);
      unsigned short hh = f2bf(hv);
      int k = w * 4 + p4;
      awrite16(sAhi[q ^ 1], c16, k, hh);
      awrite16(sAlo[q ^ 1], c16, k, f2bf(hv - bf2f(hh)));
    }
    __syncthreads();  // B1: h_lat(t) visible

    // --- slot B: decoder Wih·h_lat(t) + cell update ---
    {
      bf16x8 c0h = aread(sAhi[q ^ 1], lane, 0);
      bf16x8 c0l = aread(sAlo[q ^ 1], lane, 0);
#pragma unroll
      for (int n = 0; n < 2; ++n) {
        dac[n] = MFMA(dwh[n][0], c0h, dac[n]);
        dac[n] = MFMA(dwl[n][0], c0h, dac[n]);
        dac[n] = MFMA(dwh[n][0], c0l, dac[n]);
        float ii = fast_sig(dac[n][0]), ff = fast_sig(dac[n][1]);
        float gg = fast_tanh(dac[n][2]), oo = fast_sig(dac[n][3]);
        cD[n] = ff * cD[n] + ii * gg;
        float hv = oo * fast_tanh(cD[n]);
        unsigned short hh = f2bf(hv);
        int k = 32 + w * 8 + n * 4 + p4;
        awrite16(sAhi[q ^ 1], c16, k, hh);
        awrite16(sAlo[q ^ 1], c16, k, f2bf(hv - bf2f(hh)));
      }
    }
    __syncthreads();  // B2: h_dec(t) visible
    q ^= 1;
  }

  // final projection (t = 99) from buf q chunks 1,2
  if (w < 3) {
    bf16x8 d1h = aread(sAhi[q], lane, 1), d1l = aread(sAlo[q], lane, 1);
    bf16x8 d2h = aread(sAhi[q], lane, 2), d2l = aread(sAlo[q], lane, 2);
    f32x4 pac = f32x4{pbias[0], pbias[1], pbias[2], pbias[3]};
    pac = MFMA(pwh[0], d1h, pac);
    pac = MFMA(pwl[0], d1h, pac);
    pac = MFMA(pwh[0], d1l, pac);
    pac = MFMA(pwh[1], d2h, pac);
    pac = MFMA(pwl[1], d2h, pac);
    pac = MFMA(pwh[1], d2l, pac);
#pragma unroll
    for (int r = 0; r < 4; ++r) {
      int f = w * 16 + p4 * 4 + r;
      if (f < 40)
        out[((size_t)(bbase + c16) * 100 + 99) * 40 + f] = pac[r];
    }
  }
}

extern "C" void kernel_launch(void* const* d_in, const int* in_sizes, int n_in,
                              void* d_out, int out_size, void* d_ws, size_t ws_size,
                              hipStream_t stream) {
  const float* x    = (const float*)d_in[0];
  const float* eWih = (const float*)d_in[1];
  const float* eWhh = (const float*)d_in[2];
  const float* eb   = (const float*)d_in[3];
  const float* lWih = (const float*)d_in[4];
  const float* lWhh = (const float*)d_in[5];
  const float* lb   = (const float*)d_in[6];
  const float* dWih = (const float*)d_in[7];
  const float* dWhh = (const float*)d_in[8];
  const float* db   = (const float*)d_in[9];
  const float* oW   = (const float*)d_in[10];
  const float* ob   = (const float*)d_in[11];
  float* out = (float*)d_out;

  lstm_ae_mfma2<<<256, 512, 0, stream>>>(x, eWih, eWhh, eb, lWih, lWhh, lb,
                                         dWih, dWhh, db, oW, ob, out);
}

// Round 4
// 181.533 us; speedup vs baseline: 6.6152x; 1.1165x over previous
//
#include <hip/hip_runtime.h>
#include <hip/hip_bf16.h>
#include <cstddef>

typedef __attribute__((ext_vector_type(8))) short bf16x8;
typedef __attribute__((ext_vector_type(4))) float f32x4;

#define MFMA(a, b, c) __builtin_amdgcn_mfma_f32_16x16x32_bf16((a), (b), (c), 0, 0, 0)

static __device__ __forceinline__ unsigned short f2bf(float f) {
  __hip_bfloat16 b = __float2bfloat16(f);
  return __builtin_bit_cast(unsigned short, b);
}
static __device__ __forceinline__ float bf2f(unsigned short h) {
  unsigned u = ((unsigned)h) << 16;
  return __builtin_bit_cast(float, u);
}
static __device__ __forceinline__ float fast_sig(float x) {
  return __builtin_amdgcn_rcpf(1.0f + __expf(-x));
}
static __device__ __forceinline__ float fast_tanh(float x) {
  return 2.0f * __builtin_amdgcn_rcpf(1.0f + __expf(-2.0f * x)) - 1.0f;
}

// Activation buffer: [16 batch rows][256 B = 128 bf16 k-slots], XOR-swizzled per row.
// B-fragment (cols = batch): lane holds col b=lane&15, k = kc*32 + (lane>>4)*8 + {0..7}.
static __device__ __forceinline__ bf16x8 aread(const char* base, int lane, int kc) {
  int b = lane & 15, g = lane >> 4;
  int off = (kc * 64 + g * 16) ^ ((b & 7) << 4);
  return *(const bf16x8*)(base + b * 256 + off);
}
static __device__ __forceinline__ void awrite16(char* base, int b, int k, unsigned short v) {
  int off = (2 * k) ^ ((b & 7) << 4);
  *(unsigned short*)(base + b * 256 + off) = v;
}
// paired write: k even, writes k-slots {k, k+1} as one b32 (stays inside one 16B swizzle unit)
static __device__ __forceinline__ void awrite32(char* base, int b, int k, unsigned v) {
  int off = (2 * k) ^ ((b & 7) << 4);
  *(unsigned*)(base + b * 256 + off) = v;
}

// 8 waves. Weights = A-operand (rows = ghat) in VGPRs; activations = B-operand (cols = batch)
// in LDS. C/D: lane c16 = batch, rows p4*4+r = the 4 gates of unit u = w*8+p4*2+n  ->
// in-register cell update, h k-slot = identity (unit u at slot base+u), n=0/1 k-adjacent
// so h hi/lo pairs store as single b32. Encoder: 1 barrier/step. Phase 2: 1 barrier/iter
// via lagged pipeline (latent t=i | decoder t=i-1 | projection t=i-2).
extern "C" __global__ __launch_bounds__(512, 2)
void lstm_ae_mfma3(const float* __restrict__ x,
                   const float* __restrict__ eWih, const float* __restrict__ eWhh, const float* __restrict__ eb,
                   const float* __restrict__ lWih, const float* __restrict__ lWhh, const float* __restrict__ lb,
                   const float* __restrict__ dWih, const float* __restrict__ dWhh, const float* __restrict__ db,
                   const float* __restrict__ oW,  const float* __restrict__ ob,
                   float* __restrict__ out)
{
  __shared__ __align__(16) char sAhi[2][4096];
  __shared__ __align__(16) char sAlo[2][4096];

  const int tid  = threadIdx.x;
  const int lane = tid & 63;
  const int w    = tid >> 6;        // wave 0..7
  const int c16  = lane & 15;       // batch
  const int p4   = lane >> 4;
  const int bbase = blockIdx.x * 16;

  // ---------- zero both buffers ----------
  {
    f32x4 z = {0.f, 0.f, 0.f, 0.f};
    *(f32x4*)(&sAhi[0][0] + tid * 16) = z;
    *(f32x4*)(&sAlo[0][0] + tid * 16) = z;
  }

  // ---------- encoder weights: A-frags. tile-row tr -> (u = w*8+(tr>>2)*2+n, g = tr&3) ----------
  // k: 0..39 = x, 64..127 = h_enc (slot 64+u, identity in u)
  bf16x8 ewh[2][4], ewl[2][4];
  float ebias[2][4];
#pragma unroll
  for (int n = 0; n < 2; ++n) {
    int tr = c16;
    int u = w * 8 + (tr >> 2) * 2 + n;
    int ga = tr & 3;
#pragma unroll
    for (int r = 0; r < 4; ++r) ebias[n][r] = eb[r * 64 + (w * 8 + p4 * 2 + n)];
#pragma unroll
    for (int kc = 0; kc < 4; ++kc) {
      bf16x8 hi, lo;
#pragma unroll
      for (int e = 0; e < 8; ++e) {
        int k = kc * 32 + p4 * 8 + e;
        float v = 0.f;
        if (k < 40)       v = eWih[(ga * 64 + u) * 40 + k];
        else if (k >= 64) v = eWhh[(ga * 64 + u) * 64 + (k - 64)];
        unsigned short hh = f2bf(v);
        hi[e] = (short)hh;
        lo[e] = (short)f2bf(v - bf2f(hh));
      }
      ewh[n][kc] = hi; ewl[n][kc] = lo;
    }
  }

  __syncthreads();  // zeros visible

  // ---------- stage x_0 into buf 0 ----------
  if (tid < 160) {
    int b = tid / 10, f4 = tid - b * 10;
    f32x4 ld = *(const f32x4*)(x + ((size_t)(bbase + b) * 100 + 0) * 40 + f4 * 4);
    unsigned long long ph = 0, pl = 0;
#pragma unroll
    for (int e = 0; e < 4; ++e) {
      unsigned short hh = f2bf(ld[e]);
      unsigned short ll = f2bf(ld[e] - bf2f(hh));
      ph |= (unsigned long long)hh << (16 * e);
      pl |= (unsigned long long)ll << (16 * e);
    }
    int off = (f4 * 8) ^ ((b & 7) << 4);
    *(unsigned long long*)(sAhi[0] + b * 256 + off) = ph;
    *(unsigned long long*)(sAlo[0] + b * 256 + off) = pl;
  }

  float cE[2] = {0.f, 0.f};
  int q = 0;
  __syncthreads();

  // ================= PHASE 1: encoder, 1 barrier/step =================
#pragma unroll 1
  for (int t = 0; t < 100; ++t) {
    f32x4 xld;
    int sb = 0, sf4 = 0;
    const bool stager = (tid < 160);
    if (stager) {
      int tn = (t + 1 < 100) ? t + 1 : 99;
      sb = tid / 10; sf4 = tid - sb * 10;
      xld = *(const f32x4*)(x + ((size_t)(bbase + sb) * 100 + tn) * 40 + sf4 * 4);
    }

    f32x4 acc[2], acc2[2];
#pragma unroll
    for (int n = 0; n < 2; ++n) {
      acc[n]  = f32x4{ebias[n][0], ebias[n][1], ebias[n][2], ebias[n][3]};
      acc2[n] = f32x4{0.f, 0.f, 0.f, 0.f};
    }
    const char* Ah = sAhi[q];
    const char* Al = sAlo[q];
#pragma unroll
    for (int kc = 0; kc < 4; ++kc) {
      bf16x8 ah = aread(Ah, lane, kc);
      bf16x8 al = aread(Al, lane, kc);
#pragma unroll
      for (int n = 0; n < 2; ++n) {
        f32x4 t0 = (kc < 2) ? acc[n] : acc2[n];   // constant-folded under unroll
        t0 = MFMA(ewh[n][kc], ah, t0);
        t0 = MFMA(ewl[n][kc], ah, t0);
        t0 = MFMA(ewh[n][kc], al, t0);
        if (kc < 2) acc[n] = t0; else acc2[n] = t0;
      }
    }

    char* AhN = sAhi[q ^ 1];
    char* AlN = sAlo[q ^ 1];
    unsigned short hh[2], hl[2];
#pragma unroll
    for (int n = 0; n < 2; ++n) {
      f32x4 gv = acc[n] + acc2[n];
      float ii = fast_sig(gv[0]), ff = fast_sig(gv[1]);
      float gg = fast_tanh(gv[2]), oo = fast_sig(gv[3]);
      cE[n] = ff * cE[n] + ii * gg;
      float hv = oo * fast_tanh(cE[n]);
      hh[n] = f2bf(hv);
      hl[n] = f2bf(hv - bf2f(hh[n]));
    }
    awrite32(AhN, c16, 64 + w * 8 + p4 * 2, (unsigned)hh[0] | ((unsigned)hh[1] << 16));
    awrite32(AlN, c16, 64 + w * 8 + p4 * 2, (unsigned)hl[0] | ((unsigned)hl[1] << 16));

    if (stager) {
      unsigned long long ph = 0, pl = 0;
#pragma unroll
      for (int e = 0; e < 4; ++e) {
        unsigned short hhx = f2bf(xld[e]);
        unsigned short llx = f2bf(xld[e] - bf2f(hhx));
        ph |= (unsigned long long)hhx << (16 * e);
        pl |= (unsigned long long)llx << (16 * e);
      }
      int off = (sf4 * 8) ^ ((sb & 7) << 4);
      *(unsigned long long*)(AhN + sb * 256 + off) = ph;
      *(unsigned long long*)(AlN + sb * 256 + off) = pl;
    }
    __syncthreads();
    q ^= 1;
  }

  // ================= xg = lb + lWih @ h_enc_last =================
  f32x4 xga;
  {
    int tr = c16;
    int u = w * 4 + (tr >> 2), ga = tr & 3;
    int ul = w * 4 + p4;
    xga = f32x4{lb[ul], lb[32 + ul], lb[64 + ul], lb[96 + ul]};
#pragma unroll
    for (int kci = 0; kci < 2; ++kci) {
      bf16x8 hi, lo;
#pragma unroll
      for (int e = 0; e < 8; ++e) {
        float v = lWih[(ga * 32 + u) * 64 + kci * 32 + p4 * 8 + e];
        unsigned short hh = f2bf(v);
        hi[e] = (short)hh;
        lo[e] = (short)f2bf(v - bf2f(hh));
      }
      bf16x8 ah = aread(sAhi[q], lane, 2 + kci);
      bf16x8 al = aread(sAlo[q], lane, 2 + kci);
      xga = MFMA(hi, ah, xga);
      xga = MFMA(lo, ah, xga);
      xga = MFMA(hi, al, xga);
    }
  }
  __syncthreads();  // done reading h_enc

  // re-zero both buffers (h_lat(-1) = h_dec(-1) = h_dec(-2) = 0)
  {
    f32x4 z = {0.f, 0.f, 0.f, 0.f};
    *(f32x4*)(&sAhi[0][0] + tid * 16) = z;
    *(f32x4*)(&sAlo[0][0] + tid * 16) = z;
  }

  // ---------- phase-2 weights ----------
  // latent Whh: rows = latent ghat (u = w*4 + (tr>>2), g = tr&3), k 0..31 = h_lat slot u
  bf16x8 lwh, lwl;
  {
    int tr = c16;
    int u = w * 4 + (tr >> 2), ga = tr & 3;
    bf16x8 hi, lo;
#pragma unroll
    for (int e = 0; e < 8; ++e) {
      float v = lWhh[(ga * 32 + u) * 32 + p4 * 8 + e];
      unsigned short hh = f2bf(v);
      hi[e] = (short)hh;
      lo[e] = (short)f2bf(v - bf2f(hh));
    }
    lwh = hi; lwl = lo;
  }
  // decoder: rows -> (u = w*8+(tr>>2)*2+n, g = tr&3); k: 0..31 h_lat (Wih), 32..95 h_dec (Whh)
  bf16x8 dwh[2][3], dwl[2][3];
  float dbias[2][4];
#pragma unroll
  for (int n = 0; n < 2; ++n) {
    int tr = c16;
    int u = w * 8 + (tr >> 2) * 2 + n;
    int ga = tr & 3;
#pragma unroll
    for (int r = 0; r < 4; ++r) dbias[n][r] = db[r * 64 + (w * 8 + p4 * 2 + n)];
#pragma unroll
    for (int kc = 0; kc < 3; ++kc) {
      bf16x8 hi, lo;
#pragma unroll
      for (int e = 0; e < 8; ++e) {
        int k = kc * 32 + p4 * 8 + e;
        float v = (k < 32) ? dWih[(ga * 64 + u) * 32 + k]
                           : dWhh[(ga * 64 + u) * 64 + (k - 32)];
        unsigned short hh = f2bf(v);
        hi[e] = (short)hh;
        lo[e] = (short)f2bf(v - bf2f(hh));
      }
      dwh[n][kc] = hi; dwl[n][kc] = lo;
    }
  }
  // projection: rows = feature f (waves 0..2), k chunks 1,2 = h_dec slots 32..95
  bf16x8 pwh[2], pwl[2];
  float pbias[4];
#pragma unroll
  for (int r = 0; r < 4; ++r) {
    int f = w * 16 + p4 * 4 + r;
    pbias[r] = (w < 3 && f < 40) ? ob[f] : 0.0f;
  }
  if (w < 3) {
    int f = w * 16 + c16;
#pragma unroll
    for (int kci = 0; kci < 2; ++kci) {
      bf16x8 hi, lo;
#pragma unroll
      for (int e = 0; e < 8; ++e) {
        float v = (f < 40) ? oW[f * 64 + kci * 32 + p4 * 8 + e] : 0.0f;
        unsigned short hh = f2bf(v);
        hi[e] = (short)hh;
        lo[e] = (short)f2bf(v - bf2f(hh));
      }
      pwh[kci] = hi; pwl[kci] = lo;
    }
  }

  float cL = 0.f;
  float cD[2] = {0.f, 0.f};
  __syncthreads();

  // ================= PHASE 2: lagged pipeline, 1 barrier/iter =================
  // iter i: latent t=i | decoder t=i-1 | projection t=i-2.
  // h_lat(t) -> buf[t&1] k 0..31; h_dec(t) -> buf[t&1] k 32..95.
#pragma unroll 1
  for (int i = 0; i < 102; ++i) {
    const int pa = i & 1;
    bf16x8 c0h = aread(sAhi[pa ^ 1], lane, 0), c0l = aread(sAlo[pa ^ 1], lane, 0);
    bf16x8 d1h = aread(sAhi[pa], lane, 1),     d1l = aread(sAlo[pa], lane, 1);
    bf16x8 d2h = aread(sAhi[pa], lane, 2),     d2l = aread(sAlo[pa], lane, 2);

    // --- latent step t=i (reads h_lat(i-1) = c0) ---
    if (i < 100) {
      f32x4 lac = xga;
      lac = MFMA(lwh, c0h, lac);
      lac = MFMA(lwl, c0h, lac);
      lac = MFMA(lwh, c0l, lac);
      float ii = fast_sig(lac[0]), ff = fast_sig(lac[1]);
      float gg = fast_tanh(lac[2]), oo = fast_sig(lac[3]);
      cL = ff * cL + ii * gg;
      float hv = oo * fast_tanh(cL);
      unsigned short hhh = f2bf(hv);
      awrite16(sAhi[pa], c16, w * 4 + p4, hhh);
      awrite16(sAlo[pa], c16, w * 4 + p4, f2bf(hv - bf2f(hhh)));
    }

    // --- decoder step t=i-1 (reads h_lat(i-1) = c0, h_dec(i-2) = d1,d2) ---
    if (i >= 1 && i < 101) {
      unsigned short hh[2], hl[2];
#pragma unroll
      for (int n = 0; n < 2; ++n) {
        f32x4 dac = f32x4{dbias[n][0], dbias[n][1], dbias[n][2], dbias[n][3]};
        dac = MFMA(dwh[n][0], c0h, dac);
        dac = MFMA(dwl[n][0], c0h, dac);
        dac = MFMA(dwh[n][0], c0l, dac);
        dac = MFMA(dwh[n][1], d1h, dac);
        dac = MFMA(dwl[n][1], d1h, dac);
        dac = MFMA(dwh[n][1], d1l, dac);
        dac = MFMA(dwh[n][2], d2h, dac);
        dac = MFMA(dwl[n][2], d2h, dac);
        dac = MFMA(dwh[n][2], d2l, dac);
        float ii = fast_sig(dac[0]), ff = fast_sig(dac[1]);
        float gg = fast_tanh(dac[2]), oo = fast_sig(dac[3]);
        cD[n] = ff * cD[n] + ii * gg;
        float hv = oo * fast_tanh(cD[n]);
        hh[n] = f2bf(hv);
        hl[n] = f2bf(hv - bf2f(hh[n]));
      }
      awrite32(sAhi[pa ^ 1], c16, 32 + w * 8 + p4 * 2, (unsigned)hh[0] | ((unsigned)hh[1] << 16));
      awrite32(sAlo[pa ^ 1], c16, 32 + w * 8 + p4 * 2, (unsigned)hl[0] | ((unsigned)hl[1] << 16));
    }

    // --- projection t=i-2 (reads h_dec(i-2) = d1,d2; shares the reads) ---
    if (i >= 2 && w < 3) {
      f32x4 pac = f32x4{pbias[0], pbias[1], pbias[2], pbias[3]};
      pac = MFMA(pwh[0], d1h, pac);
      pac = MFMA(pwl[0], d1h, pac);
      pac = MFMA(pwh[0], d1l, pac);
      pac = MFMA(pwh[1], d2h, pac);
      pac = MFMA(pwl[1], d2h, pac);
      pac = MFMA(pwh[1], d2l, pac);
#pragma unroll
      for (int r = 0; r < 4; ++r) {
        int f = w * 16 + p4 * 4 + r;
        if (f < 40)
          out[((size_t)(bbase + c16) * 100 + (i - 2)) * 40 + f] = pac[r];
      }
    }
    __syncthreads();
  }
}

extern "C" void kernel_launch(void* const* d_in, const int* in_sizes, int n_in,
                              void* d_out, int out_size, void* d_ws, size_t ws_size,
                              hipStream_t stream) {
  const float* x    = (const float*)d_in[0];
  const float* eWih = (const float*)d_in[1];
  const float* eWhh = (const float*)d_in[2];
  const float* eb   = (const float*)d_in[3];
  const float* lWih = (const float*)d_in[4];
  const float* lWhh = (const float*)d_in[5];
  const float* lb   = (const float*)d_in[6];
  const float* dWih = (const float*)d_in[7];
  const float* dWhh = (const float*)d_in[8];
  const float* db   = (const float*)d_in[9];
  const float* oW   = (const float*)d_in[10];
  const float* ob   = (const float*)d_in[11];
  float* out = (float*)d_out;

  lstm_ae_mfma3<<<256, 512, 0, stream>>>(x, eWih, eWhh, eb, lWih, lWhh, lb,
                                         dWih, dWhh, db, oW, ob, out);
}